// Round 14
// baseline (516.426 us; speedup 1.0000x reference)
//
#include <hip/hip_runtime.h>
#include <hip/hip_bf16.h>
#include <cstdint>
#include <cstddef>

using bf16 = __hip_bfloat16;
#define DEV __device__ __forceinline__

typedef short s16x8 __attribute__((ext_vector_type(8)));
typedef float f32x4 __attribute__((ext_vector_type(4)));

DEV float b2f(bf16 x){ return __bfloat162float(x); }
DEV bf16  f2b(float x){ return __float2bfloat16(x); }
DEV float u2f(unsigned u){ union{unsigned u; float f;} c; c.u=u; return c.f; }
DEV unsigned f2u(float f){ union{float f; unsigned u;} c; c.f=f; return c.u; }
DEV unsigned short f2bu(float f){ unsigned u = f2u(f); u += 0x7FFFu + ((u>>16)&1u); return (unsigned short)(u>>16); }
DEV float sigm(float x){ return 1.f/(1.f+__expf(-x)); }
DEV int get_bf(const void* ln1g){ return ((*(const unsigned*)ln1g) & 0xFFFFu) == 0x3F80u; }

DEV float ld(const void* p, long i, int bf){
  return bf ? b2f(((const bf16*)p)[i]) : ((const float*)p)[i];
}
DEV void st(void* p, long i, float v, int bf){
  if (bf) ((bf16*)p)[i] = f2b(v); else ((float*)p)[i] = v;
}

constexpr float IMGX = 100.0f;
constexpr float IMGY = 56.0f;
constexpr float LOG_EPS = -15.942385f;
constexpr float BIN = 53.0f/1056.0f;
constexpr int NC = 35;
constexpr int CK = 160;

// ---- fp32 weight buffer offsets (floats) ----
constexpr int WO_SAQKVW = 0;
constexpr int WO_SAQKVB = 98304;
constexpr int WO_SAOW   = 99072;
constexpr int WO_SAOB   = 131840;
constexpr int WO_CAQKVW = 132096;
constexpr int WO_CAQKVB = 230400;
constexpr int WO_CAOW   = 231168;
constexpr int WO_CAOB   = 263936;
constexpr int WO_LN1G   = 264192;
constexpr int WO_LN1B   = 264448;
constexpr int WO_LN2G   = 264704;
constexpr int WO_LN2B   = 264960;
constexpr int WO_LN3G   = 265216;
constexpr int WO_LN3B   = 265472;
constexpr int WO_FW1    = 265728;
constexpr int WO_FB1    = 331264;
constexpr int WO_FW2    = 331776;
constexpr int WO_FB2    = 397312;
constexpr int WO_QW1    = 397568;
constexpr int WO_QB1    = 398080;
constexpr int WO_QW2    = 398336;
constexpr int WO_QB2    = 431104;
constexpr int WO_KW1    = 431360;
constexpr int WO_KB1    = 431872;
constexpr int WO_KB2    = 432128;
constexpr int WO_PW1    = 432384;
constexpr int WO_PB1    = 448768;
constexpr int WO_PW2    = 448896;
constexpr int WO_PB2    = 449664;
constexpr int W_TOTAL   = 449680;

// ---- workspace layout (floats) ----
constexpr size_t OFF_Q    = 0;
constexpr size_t OFF_QPE  = 25600;
constexpr size_t OFF_QCA  = 51200;
constexpr size_t OFF_TMP  = 76800;
constexpr size_t OFF_PM   = 153600;
constexpr size_t OFF_PS   = 209600;
constexpr size_t OFF_PO   = 265600;
constexpr size_t OFF_FPOS = 1161600;
constexpr size_t OFF_CTR  = 1172800;
constexpr size_t OFF_SIG  = 1173200;
constexpr size_t OFF_QL   = 1173400;
constexpr size_t OFF_WB   = 1174624;
constexpr size_t F_TOTAL  = OFF_WB + W_TOTAL;
// bf16 region (elements):
constexpr size_t B_KEYS = 0;          // 4300800
constexpr size_t B_KPE  = 4300800;    // 2*716800
constexpr size_t B_WKVT = 5734400;    // 65536
constexpr size_t B_KW2T = 5799936;    // 32768
constexpr size_t B_KVB  = 5832704;
constexpr size_t KV_LSTRIDE = 8601600;
constexpr size_t NEED_BIG = F_TOTAL*4 + (B_KVB + 2*KV_LSTRIDE)*2;

DEV void unpack2(unsigned u, float* f){ f[0]=u2f(u<<16); f[1]=u2f(u&0xffff0000u); }

DEV float wsum64(float v){
  #pragma unroll
  for (int off=32; off; off>>=1) v += __shfl_xor(v, off);
  return v;
}

// ================= params bundle =================
struct P {
  const void *nifp, *iff, *niqp, *iqf, *l2i, *ln1g;
  const int *view, *qlp;
  const float *wb;
  float *q, *qpe, *qca, *tmp, *pm, *ps, *po, *fpos, *ctr, *sig2;
  const bf16 *kw2T, *wkvT, *keys;
  bf16 *kvb, *kpe;
  void *out;
};

// ================= weight conversion + qlist + weight transposes =================
struct Seg { const void* src; int off; int n; };
struct CvtArgs { Seg s[29]; };

__global__ void k_cvt(CvtArgs a, float* dst, int* qlp, const int* view,
                      const void* caw, const void* kw2,
                      bf16* wkvT, bf16* kw2T, const void* ln1g){
  int bf = get_bf(ln1g);
  int bx = blockIdx.x, t = threadIdx.x;
  if (bx == 29){
    if (blockIdx.y == 0 && t < 6){
      int cnt = 0;
      for (int i = 0; i < 200; ++i)
        if (view[i] == t) qlp[8 + t*200 + cnt++] = i;
      qlp[t] = cnt;
    }
    return;
  }
  if (bx == 30){
    for (int i = blockIdx.y*256 + t; i < 65536; i += 8*256){
      int l = i >> 15, r = i & 32767, c = r >> 7, k = r & 127;
      wkvT[i] = f2b(ld(caw, (long)l*49152 + (long)k*384 + 128 + c, bf));
    }
    return;
  }
  if (bx == 31){
    for (int i = blockIdx.y*256 + t; i < 32768; i += 8*256){
      int l = i >> 14, r = i & 16383, c = r >> 7, k = r & 127;
      kw2T[i] = f2b(ld(kw2, (long)l*16384 + (long)k*128 + c, bf));
    }
    return;
  }
  Seg sg = a.s[bx];
  for (int i = blockIdx.y*blockDim.x + t; i < sg.n; i += gridDim.y*blockDim.x)
    dst[sg.off + i] = ld(sg.src, i, bf);
}

// ================= stage bodies =================

DEV void transpose_block(int b, int t, unsigned char* smem, const P& p, int bf){
  float (*ts)[33] = (float(*)[33])smem;
  int k0 = (b % 175)*32;
  int c0 = ((b/175) & 3)*32;
  int v  = b / 700;
  int tx = t & 31, ty = t >> 5;
  bf16* keys = const_cast<bf16*>(p.keys);
  #pragma unroll
  for (int i=0;i<4;++i){
    int c = c0 + ty + i*8;
    ts[ty+i*8][tx] = ld(p.iff, (long)(v*128 + c)*5600 + k0 + tx, bf);
  }
  __syncthreads();
  #pragma unroll
  for (int i=0;i<4;++i){
    int k = k0 + ty + i*8;
    keys[(size_t)(v*5600 + k)*128 + c0 + tx] = f2b(ts[tx][ty+i*8]);
  }
}

DEV void prep_block(int n, int t, unsigned char* smem, const P& p, int bf){
  float* M   = (float*)smem;
  float* cs  = M + 16;
  float* xs  = cs + 2;
  float* acc = xs + 128;
  float* bbv = acc + 768;
  if (t < 28){
    int k = n*28 + t;
    p.fpos[2*k]   = sigm(ld(p.nifp,2*k,bf))*IMGX - 0.5f;
    p.fpos[2*k+1] = sigm(ld(p.nifp,2*k+1,bf))*IMGY - 0.5f;
  }
  if (t < 128){
    float xv = ld(p.iqf, (long)t*200 + n, bf);
    p.q[(size_t)n*128 + t] = xv;
    xs[t] = xv;
  }
  if (t == 0){
    float p0 = ld(p.niqp,2*n,bf), p1 = ld(p.niqp,2*n+1,bf);
    float cx = sigm(p0)*IMGX, cy = sigm(p1)*IMGY;
    p.ctr[2*n] = cx; p.ctr[2*n+1] = cy;
    cs[0] = cx; cs[1] = cy;
    st(p.out, 25600 + 2*n,   p0, bf);
    st(p.out, 25600 + 2*n+1, p1, bf);
    int v = p.view[n];
    float a[4][8];
    for (int i=0;i<4;++i)
      for (int jj=0;jj<4;++jj){ a[i][jj] = ld(p.l2i, v*16+i*4+jj, bf); a[i][4+jj] = (i==jj)?1.f:0.f; }
    for (int col=0; col<4; ++col){
      int pi = col; float best = fabsf(a[col][col]);
      for (int r=col+1;r<4;++r){ float tt=fabsf(a[r][col]); if (tt>best){best=tt;pi=r;} }
      if (pi!=col) for (int jj=0;jj<8;++jj){ float tt=a[col][jj]; a[col][jj]=a[pi][jj]; a[pi][jj]=tt; }
      float inv = 1.f/a[col][col];
      for (int jj=0;jj<8;++jj) a[col][jj]*=inv;
      for (int r=0;r<4;++r){
        if (r==col) continue;
        float f = a[r][col];
        for (int jj=0;jj<8;++jj) a[r][jj] -= f*a[col][jj];
      }
    }
    for (int i=0;i<4;++i) for (int jj=0;jj<4;++jj) M[i*4+jj] = a[i][4+jj];
  }
  __syncthreads();
  if (t < 32){
    int d = t;
    float px = cs[0]*8.f, py = cs[1]*8.f;
    float dep = 1.f + BIN * (float)d * (float)(d+1);
    float x = px*dep, y = py*dep;
    #pragma unroll
    for (int i=0;i<3;++i){
      float val = M[i*4]*x + M[i*4+1]*y + M[i*4+2]*dep + M[i*4+3];
      st(p.out, 26000 + n*96 + d*3 + i, val, bf);
    }
  }
  if (t < 128){
    float a = p.wb[WO_PB1 + t];
    const float* W = p.wb + WO_PW1;
    for (int k = 0; k < 128; ++k) a = fmaf(xs[k], W[k*128 + t], a);
    float x = fmaxf(a, 0.f);
    #pragma unroll
    for (int c=0;c<6;++c) acc[c*128+t] = x * p.wb[WO_PW2 + t*6 + c];
  }
  __syncthreads();
  for (int off=64; off; off>>=1){
    if (t < off){
      #pragma unroll
      for (int c=0;c<6;++c) acc[c*128+t] += acc[c*128+t+off];
    }
    __syncthreads();
  }
  if (t < 6) bbv[t] = acc[t*128] + p.wb[WO_PB2 + t];
  __syncthreads();
  if (t == 0){
    float dxv = sigm(bbv[2]) * IMGX;
    float dyv = sigm(bbv[3]) * IMGY;
    float rad = ceilf(sqrtf(dxv*dxv + dyv*dyv) * 0.5f);
    float sg = (rad*2.f + 1.f) * (1.f/6.f);
    p.sig2[n] = 1.f/(2.f*sg*sg);
  }
}

DEV void kpe_block(int b, int t, unsigned char* smem, const P& p, int l, int bf){
  constexpr int XP = 136;
  unsigned short* xs = (unsigned short*)smem;
  float2* pr = (float2*)(xs + 64*XP);
  bf16* kpeL = p.kpe + (size_t)l*716800;
  int r0 = b * 64;
  if (t < 64){
    int k = r0 + t; if (k > 5599) k = 5599;
    pr[t] = make_float2(ld(p.nifp,2*k,bf), ld(p.nifp,2*k+1,bf));
  }
  __syncthreads();
  const float* w1 = p.wb + WO_KW1 + l*256;
  const float* b1 = p.wb + WO_KB1 + l*128;
  for (int idx = t; idx < 64*64; idx += 256){
    int r = idx >> 6, c2 = (idx & 63)*2;
    float2 pp = pr[r];
    #pragma unroll
    for (int u=0;u<2;++u){
      int c = c2+u;
      float a = fmaf(pp.x, w1[c], fmaf(pp.y, w1[128+c], b1[c]));
      xs[r*XP + c] = f2bu(fmaxf(a, 0.f));
    }
  }
  int wv = t >> 6;
  int lane = t & 63;
  int l16 = lane & 15, quad = lane >> 4;
  __syncthreads();
  f32x4 acc[4][2];
  #pragma unroll
  for (int mt=0;mt<4;++mt)
    #pragma unroll
    for (int nt=0;nt<2;++nt) acc[mt][nt] = (f32x4){0.f,0.f,0.f,0.f};
  #pragma unroll
  for (int kc = 0; kc < 4; ++kc){
    s16x8 bfr[2];
    #pragma unroll
    for (int nt = 0; nt < 2; ++nt){
      int col = wv*32 + nt*16 + l16;
      bfr[nt] = *(const s16x8*)&p.kw2T[((size_t)l*128 + col)*128 + kc*32 + quad*8];
    }
    s16x8 afr[4];
    #pragma unroll
    for (int mt = 0; mt < 4; ++mt)
      afr[mt] = *(const s16x8*)&xs[(mt*16 + l16)*XP + kc*32 + quad*8];
    #pragma unroll
    for (int mt = 0; mt < 4; ++mt)
      #pragma unroll
      for (int nt = 0; nt < 2; ++nt)
        acc[mt][nt] = __builtin_amdgcn_mfma_f32_16x16x32_bf16(afr[mt], bfr[nt], acc[mt][nt], 0, 0, 0);
  }
  float bv[2];
  #pragma unroll
  for (int nt=0;nt<2;++nt) bv[nt] = p.wb[WO_KB2 + l*128 + wv*32 + nt*16 + l16];
  #pragma unroll
  for (int mt = 0; mt < 4; ++mt)
    #pragma unroll
    for (int i = 0; i < 4; ++i){
      int gr = r0 + mt*16 + quad*4 + i;
      if (gr < 5600){
        #pragma unroll
        for (int nt = 0; nt < 2; ++nt)
          kpeL[(size_t)gr*128 + wv*32 + nt*16 + l16] = f2b(acc[mt][nt][i] + bv[nt]);
      }
    }
}

DEV void saqkv_body(int n, int t, float* hsx, float* xq, const P& p, int l, int bf, float qval){
  if (t < 128){
    float p0 = ld(p.niqp,2*n,bf), p1 = ld(p.niqp,2*n+1,bf);
    float a = fmaf(p0, p.wb[WO_QW1 + l*256 + t], fmaf(p1, p.wb[WO_QW1 + l*256 + 128 + t], p.wb[WO_QB1 + l*128 + t]));
    hsx[t] = fmaxf(a, 0.f);
  }
  __syncthreads();
  if (t < 128){
    const float* W = p.wb + WO_QW2 + l*16384;
    float a = p.wb[WO_QB2 + l*128 + t];
    for (int k = 0; k < 128; ++k) a = fmaf(hsx[k], W[k*128 + t], a);
    p.qpe[(size_t)n*128 + t] = a;
    xq[t] = qval + a;
  }
  __syncthreads();
  const float* W = p.wb + WO_SAQKVW + l*49152;
  for (int c = t; c < 384; c += 256){
    float acc = p.wb[WO_SAQKVB + l*384 + c];
    for (int k = 0; k < 128; ++k) acc = fmaf(xq[k], W[(long)k*384 + c], acc);
    p.tmp[(size_t)n*384 + c] = acc;
  }
}

DEV void kvproj_block(int b, int t, unsigned char* smem, const P& p, int l, int slot){
  constexpr int XP = 136;
  unsigned short* xs = (unsigned short*)smem;
  const bf16* kpeL = p.kpe + (size_t)l*716800;
  bf16* khL = p.kvb + (size_t)slot*KV_LSTRIDE;
  bf16* vhL = khL + 4300800;
  int r0 = b * 64;
  for (int idx = t; idx < 64*64; idx += 256){
    int r = idx >> 6, c2 = (idx & 63)*2;
    int gr = r0 + r;
    int v = gr / 5600; int k = gr - v*5600;
    float a0 = b2f(p.keys[(size_t)gr*128 + c2])   + b2f(kpeL[(size_t)k*128 + c2]);
    float a1 = b2f(p.keys[(size_t)gr*128 + c2+1]) + b2f(kpeL[(size_t)k*128 + c2+1]);
    xs[r*XP + c2]   = f2bu(a0);
    xs[r*XP + c2+1] = f2bu(a1);
  }
  int wv = t >> 6;
  int lane = t & 63;
  int l16 = lane & 15, quad = lane >> 4;
  __syncthreads();
  f32x4 acc[4][4];
  #pragma unroll
  for (int mt=0;mt<4;++mt)
    #pragma unroll
    for (int nt=0;nt<4;++nt) acc[mt][nt] = (f32x4){0.f,0.f,0.f,0.f};
  #pragma unroll
  for (int kc = 0; kc < 4; ++kc){
    s16x8 bfr[4];
    #pragma unroll
    for (int nt = 0; nt < 4; ++nt){
      int col = wv*64 + nt*16 + l16;
      bfr[nt] = *(const s16x8*)&p.wkvT[((size_t)l*256 + col)*128 + kc*32 + quad*8];
    }
    s16x8 afr[4];
    #pragma unroll
    for (int mt = 0; mt < 4; ++mt)
      afr[mt] = *(const s16x8*)&xs[(mt*16 + l16)*XP + kc*32 + quad*8];
    #pragma unroll
    for (int mt = 0; mt < 4; ++mt)
      #pragma unroll
      for (int nt = 0; nt < 4; ++nt)
        acc[mt][nt] = __builtin_amdgcn_mfma_f32_16x16x32_bf16(afr[mt], bfr[nt], acc[mt][nt], 0, 0, 0);
  }
  float bv[4];
  bf16* op[4];
  long ntOff[4];
  #pragma unroll
  for (int nt = 0; nt < 4; ++nt){
    int c = wv*64 + nt*16 + l16;
    bv[nt] = p.wb[WO_CAQKVB + l*384 + 128 + c];
    int sel = c >> 7, ch = c & 127;
    int h = ch >> 4, d = ch & 15;
    op[nt] = sel ? vhL : khL;
    ntOff[nt] = (long)h*89600 + d;
  }
  #pragma unroll
  for (int mt = 0; mt < 4; ++mt)
    #pragma unroll
    for (int i = 0; i < 4; ++i){
      int gr = r0 + mt*16 + quad*4 + i;
      int v = gr / 5600; int k = gr - v*5600;
      long rowOff = (long)v*716800 + (long)k*16;
      #pragma unroll
      for (int nt = 0; nt < 4; ++nt)
        op[nt][rowOff + ntOff[nt]] = f2b(acc[mt][nt][i] + bv[nt]);
    }
}

// ================= launched kernels =================

// stage1: transpose(4200) | prep(200) | kpe x2 (176) | saqkv l0 (200)
__global__ __launch_bounds__(256) void k_stage1(P p){
  __shared__ __align__(16) unsigned char smem[17920];
  int b = blockIdx.x, t = threadIdx.x;
  int bf = get_bf(p.ln1g);
  if (b < 4200){ transpose_block(b, t, smem, p, bf); return; }
  b -= 4200;
  if (b < 200){ prep_block(b, t, smem, p, bf); return; }
  b -= 200;
  if (b < 176){ kpe_block(b % 88, t, smem, p, b / 88, bf); return; }
  b -= 176;
  {
    float* hsx = (float*)smem;
    float* xq  = hsx + 128;
    float qval = (t < 128) ? ld(p.iqf, (long)t*200 + b, bf) : 0.f;
    saqkv_body(b, t, hsx, xq, p, 0, bf, qval);
  }
}

__global__ __launch_bounds__(256) void k_saq(P p, int l){
  __shared__ float hsx[128];
  __shared__ float xq[128];
  int n = blockIdx.x, t = threadIdx.x;
  int bf = get_bf(p.ln1g);
  float qval = (t < 128) ? p.q[(size_t)n*128 + t] : 0.f;
  saqkv_body(n, t, hsx, xq, p, l, bf, qval);
}

__global__ __launch_bounds__(256) void k_kvproj2(P p){
  __shared__ __align__(16) unsigned char smem[17408];
  int b = blockIdx.x;
  int l = b / 525;
  kvproj_block(b % 525, threadIdx.x, smem, p, l, l);
}
__global__ __launch_bounds__(256) void k_kvproj1(P p, int l){
  __shared__ __align__(16) unsigned char smem[17408];
  kvproj_block(blockIdx.x, threadIdx.x, smem, p, l, 0);
}

// self-attn + out-proj + LN1 + ca-q projection
__global__ __launch_bounds__(256) void k_self(P p, int l){
  __shared__ float att[128];
  __shared__ float part[256];
  __shared__ float redw[4];
  __shared__ float xs2[128];
  int n = blockIdx.x, t = threadIdx.x;
  int h = t >> 5, j = t & 31;
  int vn = p.view[n];
  float qh[16];
  #pragma unroll
  for (int d=0; d<16; ++d) qh[d] = p.tmp[(size_t)n*384 + h*16 + d] * 0.25f;
  float m = -INFINITY, s = 0.f, o[16];
  #pragma unroll
  for (int d=0; d<16; ++d) o[d]=0.f;
  for (int k = j; k < 200; k += 32){
    float l2;
    if (p.view[k] != vn){ l2 = -INFINITY; }
    else {
      const float* kr = p.tmp + (size_t)k*384 + 128 + h*16;
      l2 = 0.f;
      #pragma unroll
      for (int d=0; d<16; ++d) l2 = fmaf(qh[d], kr[d], l2);
    }
    float mn = fmaxf(m, l2);
    float ea = (m > -3.0e38f) ? __expf(m - mn) : 0.f;
    float pp = (l2 > -3.0e38f) ? __expf(l2 - mn) : 0.f;
    s = s*ea + pp;
    const float* vr = p.tmp + (size_t)k*384 + 256 + h*16;
    #pragma unroll
    for (int d=0; d<16; ++d) o[d] = o[d]*ea + pp*vr[d];
    m = mn;
  }
  float M = m;
  #pragma unroll
  for (int off=16; off>=1; off>>=1) M = fmaxf(M, __shfl_xor(M, off));
  float sc = (m > -3.0e38f) ? __expf(m - M) : 0.f;
  s *= sc;
  #pragma unroll
  for (int d=0; d<16; ++d) o[d] *= sc;
  #pragma unroll
  for (int off=16; off>=1; off>>=1){
    s += __shfl_xor(s, off);
    #pragma unroll
    for (int d=0; d<16; ++d) o[d] += __shfl_xor(o[d], off);
  }
  if (j == 0){
    float inv = (s > 0.f) ? 1.f/s : 0.f;
    #pragma unroll
    for (int d=0; d<16; ++d) att[h*16 + d] = o[d]*inv;
  }
  __syncthreads();
  int tc = t & 127, half = t >> 7;
  {
    const float* W = p.wb + WO_SAOW + l*16384;
    float a = 0.f;
    for (int k = half*64; k < half*64+64; ++k) a = fmaf(att[k], W[k*128 + tc], a);
    part[t] = a;
  }
  __syncthreads();
  float v = (t<128) ? p.q[(size_t)n*128 + t] + part[t] + part[128+t] + p.wb[WO_SAOB + l*128 + t] : 0.f;
  float sv = wsum64(v);
  if ((t&63)==0) redw[t>>6] = sv;
  __syncthreads();
  float mean = (redw[0]+redw[1]+redw[2]+redw[3]) * (1.f/128.f);
  __syncthreads();
  float d = (t<128)? v-mean : 0.f;
  sv = wsum64(d*d);
  if ((t&63)==0) redw[t>>6] = sv;
  __syncthreads();
  float var = (redw[0]+redw[1]+redw[2]+redw[3]) * (1.f/128.f);
  float r = rsqrtf(var + 1e-5f);
  if (t<128){
    float qn = d*r*p.wb[WO_LN1G + l*128 + t] + p.wb[WO_LN1B + l*128 + t];
    p.q[(size_t)n*128 + t] = qn;
    xs2[t] = qn + p.qpe[(size_t)n*128 + t];
  }
  __syncthreads();
  {
    const float* Wc = p.wb + WO_CAQKVW + l*49152;
    float a = 0.f;
    for (int k = half*64; k < half*64+64; ++k) a = fmaf(xs2[k], Wc[(long)k*384 + tc], a);
    part[t] = a;
  }
  __syncthreads();
  if (t<128)
    p.qca[(size_t)n*128 + t] = part[t] + part[128+t] + p.wb[WO_CAQKVB + l*384 + t];
}

// cross-attention partial, 512 threads = 16 query-groups
__global__ __launch_bounds__(512) void k_cross_part(P p, int slot){
  __shared__ __align__(16) unsigned short KV[CK][36];
  __shared__ float2 fp[CK];
  int ch = blockIdx.x, h = blockIdx.y, v = blockIdx.z;
  int t = threadIdx.x;
  int k0 = ch*CK;
  const bf16* khL = p.kvb + (size_t)slot*KV_LSTRIDE;
  const bf16* vhL = khL + 4300800;
  const uint2* ks = (const uint2*)(khL + ((size_t)(v*8 + h)*5600 + k0)*16);
  const uint2* vs = (const uint2*)(vhL + ((size_t)(v*8 + h)*5600 + k0)*16);
  for (int i = t; i < CK*4; i += 512){
    int key = i >> 2, part = i & 3;
    *(uint2*)&KV[key][part*4]      = ks[i];
    *(uint2*)&KV[key][16 + part*4] = vs[i];
  }
  if (t < CK) fp[t] = ((const float2*)p.fpos)[k0 + t];
  __syncthreads();
  int nq = p.qlp[v];
  const int* ql = p.qlp + 8 + v*200;
  int g = t >> 5, j = t & 31;
  for (int pp = g; pp < nq; pp += 16){
    int n = ql[pp];
    float cx = p.ctr[2*n], cy = p.ctr[2*n+1];
    float is2 = p.sig2[n];
    float qh[16];
    const float* qrow = p.qca + (size_t)n*128 + h*16;
    #pragma unroll
    for (int d=0; d<16; ++d) qh[d] = qrow[d] * 0.25f;
    float m = -INFINITY, s = 0.f, o[16];
    #pragma unroll
    for (int d=0; d<16; ++d) o[d]=0.f;
    #pragma unroll
    for (int i = 0; i < CK/32; ++i){
      int key = i*32 + j;
      float2 pxy = fp[key];
      float dx = cx - pxy.x, dy = cy - pxy.y;
      float gg = -(dx*dx + dy*dy) * is2;
      const uint2* kp = (const uint2*)&KV[key][0];
      const uint2* vp = (const uint2*)&KV[key][16];
      float kf[16], vf[16];
      #pragma unroll
      for (int u=0; u<4; ++u){
        uint2 a = kp[u]; unpack2(a.x, kf+u*4); unpack2(a.y, kf+u*4+2);
        uint2 b = vp[u]; unpack2(b.x, vf+u*4); unpack2(b.y, vf+u*4+2);
      }
      float l = gg;
      #pragma unroll
      for (int d=0; d<16; ++d) l = fmaf(qh[d], kf[d], l);
      l = (gg < LOG_EPS) ? -INFINITY : l;
      float mn = fmaxf(m, l);
      float ea = (m > -3.0e38f) ? __expf(m - mn) : 0.f;
      float pr = (l > -3.0e38f) ? __expf(l - mn) : 0.f;
      s = s*ea + pr;
      #pragma unroll
      for (int d=0; d<16; ++d) o[d] = o[d]*ea + pr*vf[d];
      m = mn;
    }
    float M = m;
    #pragma unroll
    for (int off=16; off>=1; off>>=1) M = fmaxf(M, __shfl_xor(M, off));
    float sc = (m > -3.0e38f) ? __expf(m - M) : 0.f;
    s *= sc;
    #pragma unroll
    for (int d=0; d<16; ++d) o[d] *= sc;
    #pragma unroll
    for (int off=16; off>=1; off>>=1){
      s += __shfl_xor(s, off);
      #pragma unroll
      for (int d=0; d<16; ++d) o[d] += __shfl_xor(o[d], off);
    }
    if (j == 0){
      int idx = (n*NC + ch)*8 + h;
      p.pm[idx] = M; p.ps[idx] = s;
      float4* o4 = (float4*)(p.po + (size_t)idx*16);
      o4[0] = make_float4(o[0],o[1],o[2],o[3]);
      o4[1] = make_float4(o[4],o[5],o[6],o[7]);
      o4[2] = make_float4(o[8],o[9],o[10],o[11]);
      o4[3] = make_float4(o[12],o[13],o[14],o[15]);
    }
  }
}

// tail: merge + out-proj + LN2 + FFN + LN3 + pred + bbox
__global__ __launch_bounds__(256) void k_tail(P p, int l){
  __shared__ float att[128];
  __shared__ float sm[2][128], ss[2][128], so[2][128];
  __shared__ float part[256];
  __shared__ float redw[4];
  __shared__ float xs[128];
  __shared__ float hs[256];
  __shared__ float ac6[6*128];
  __shared__ float bbv[8];
  int bf = get_bf(p.ln1g);
  int n = blockIdx.x, t = threadIdx.x;
  long outOff = (l==0) ? 45200L : 46400L;
  int last = (l==1);
  int tc = t & 127, half = t >> 7;
  {
    int h = tc >> 4, d = tc & 15;
    int c0 = half ? 18 : 0, c1 = half ? NC : 18;
    float m = -INFINITY, s = 0.f, o = 0.f;
    for (int c = c0; c < c1; ++c){
      int idx = (n*NC + c)*8 + h;
      float mc = p.pm[idx], sc = p.ps[idx], oc = p.po[(size_t)idx*16 + d];
      float mn = fmaxf(m, mc);
      float ea = (m  > -3.0e38f) ? __expf(m  - mn) : 0.f;
      float eb = (mc > -3.0e38f) ? __expf(mc - mn) : 0.f;
      s = s*ea + sc*eb;
      o = o*ea + oc*eb;
      m = mn;
    }
    sm[half][tc]=m; ss[half][tc]=s; so[half][tc]=o;
  }
  __syncthreads();
  if (t < 128){
    float m1=sm[0][t], m2=sm[1][t];
    float mn=fmaxf(m1,m2);
    float e1=(m1>-3.0e38f)?__expf(m1-mn):0.f, e2=(m2>-3.0e38f)?__expf(m2-mn):0.f;
    float s = ss[0][t]*e1 + ss[1][t]*e2;
    float o = so[0][t]*e1 + so[1][t]*e2;
    att[t] = (s>0.f)? o/s : 0.f;
  }
  __syncthreads();
  {
    const float* W = p.wb + WO_CAOW + l*16384;
    float a = 0.f;
    for (int k = half*64; k < half*64+64; ++k) a = fmaf(att[k], W[k*128 + tc], a);
    part[t] = a;
  }
  __syncthreads();
  float v = (t<128) ? p.q[(size_t)n*128 + t] + part[t] + part[128+t] + p.wb[WO_CAOB + l*128 + t] : 0.f;
  float sv = wsum64(v);
  if ((t&63)==0) redw[t>>6] = sv;
  __syncthreads();
  float mean = (redw[0]+redw[1]+redw[2]+redw[3]) * (1.f/128.f);
  __syncthreads();
  float d = (t<128)? v-mean : 0.f;
  sv = wsum64(d*d);
  if ((t&63)==0) redw[t>>6] = sv;
  __syncthreads();
  float var = (redw[0]+redw[1]+redw[2]+redw[3]) * (1.f/128.f);
  float r = rsqrtf(var + 1e-5f);
  if (t<128) xs[t] = d*r*p.wb[WO_LN2G + l*128 + t] + p.wb[WO_LN2B + l*128 + t];
  __syncthreads();
  {
    const float* W = p.wb + WO_FW1 + l*32768;
    float a = p.wb[WO_FB1 + l*256 + t];
    for (int k=0;k<128;++k) a = fmaf(xs[k], W[k*256 + t], a);
    hs[t] = fmaxf(a, 0.f);
  }
  __syncthreads();
  {
    const float* W = p.wb + WO_FW2 + l*32768;
    float a = 0.f;
    for (int k=half*128;k<half*128+128;++k) a = fmaf(hs[k], W[k*128 + tc], a);
    part[t] = a;
  }
  __syncthreads();
  v = (t<128) ? xs[t] + part[t] + part[128+t] + p.wb[WO_FB2 + l*128 + t] : 0.f;
  sv = wsum64(v);
  if ((t&63)==0) redw[t>>6] = sv;
  __syncthreads();
  mean = (redw[0]+redw[1]+redw[2]+redw[3]) * (1.f/128.f);
  __syncthreads();
  d = (t<128)? v-mean : 0.f;
  sv = wsum64(d*d);
  if ((t&63)==0) redw[t>>6] = sv;
  __syncthreads();
  var = (redw[0]+redw[1]+redw[2]+redw[3]) * (1.f/128.f);
  r = rsqrtf(var + 1e-5f);
  if (t<128){
    float q3 = d*r*p.wb[WO_LN3G + l*128 + t] + p.wb[WO_LN3B + l*128 + t];
    p.q[(size_t)n*128 + t] = q3;
    xs[t] = q3;
    if (last) st(p.out, (long)t*200 + n, q3, bf);
  }
  __syncthreads();
  {
    const float* W = p.wb + WO_PW1;
    float a = 0.f;
    for (int k=half*64;k<half*64+64;++k) a = fmaf(xs[k], W[k*128 + tc], a);
    part[t] = a;
  }
  __syncthreads();
  if (t<128){
    float x = fmaxf(part[t] + part[128+t] + p.wb[WO_PB1 + t], 0.f);
    #pragma unroll
    for (int c=0;c<6;++c) ac6[c*128+t] = x * p.wb[WO_PW2 + t*6 + c];
  }
  __syncthreads();
  for (int off=64; off; off>>=1){
    if (t < off){
      #pragma unroll
      for (int c=0;c<6;++c) ac6[c*128+t] += ac6[c*128+t+off];
    }
    __syncthreads();
  }
  if (t < 6){
    float raw = ac6[t*128] + p.wb[WO_PB2 + t];
    if (t < 2) raw += ld(p.niqp, 2*n + t, bf);
    float svv = sigm(raw);
    st(p.out, outOff + n*6 + t, svv, bf);
    bbv[t] = svv;
  }
  __syncthreads();
  if (t == 0){
    float dxv = sigm(bbv[2]) * IMGX;
    float dyv = sigm(bbv[3]) * IMGY;
    float rad = ceilf(sqrtf(dxv*dxv + dyv*dyv) * 0.5f);
    float sg = (rad*2.f + 1.f) * (1.f/6.f);
    p.sig2[n] = 1.f/(2.f*sg*sg);
  }
}

// ================= launch =================
extern "C" void kernel_launch(void* const* d_in, const int* in_sizes, int n_in,
                              void* d_out, int out_size, void* d_ws, size_t ws_size,
                              hipStream_t stream){
  const void* ln1_g = d_in[14];

  float* fw = (float*)d_ws;
  int*   qlp  = (int*)(fw + OFF_QL);
  float* wb   = fw + OFF_WB;
  bf16* bw   = (bf16*)((char*)d_ws + F_TOTAL*sizeof(float));

  P p;
  p.nifp = d_in[3]; p.iff = d_in[2]; p.niqp = d_in[1]; p.iqf = d_in[0];
  p.l2i = d_in[4]; p.ln1g = ln1_g;
  p.view = (const int*)d_in[5]; p.qlp = qlp;
  p.wb = wb;
  p.q = fw + OFF_Q; p.qpe = fw + OFF_QPE; p.qca = fw + OFF_QCA; p.tmp = fw + OFF_TMP;
  p.pm = fw + OFF_PM; p.ps = fw + OFF_PS; p.po = fw + OFF_PO;
  p.fpos = fw + OFF_FPOS; p.ctr = fw + OFF_CTR; p.sig2 = fw + OFF_SIG;
  p.keys = bw + B_KEYS; p.kpe = bw + B_KPE;
  p.wkvT = bw + B_WKVT; p.kw2T = bw + B_KW2T;
  p.kvb = bw + B_KVB;
  p.out = d_out;

  CvtArgs ca;
  ca.s[0]  = {d_in[6],  WO_SAQKVW, 98304};
  ca.s[1]  = {d_in[7],  WO_SAQKVB, 768};
  ca.s[2]  = {d_in[8],  WO_SAOW,   32768};
  ca.s[3]  = {d_in[9],  WO_SAOB,   256};
  ca.s[4]  = {d_in[10], WO_CAQKVW, 98304};
  ca.s[5]  = {d_in[11], WO_CAQKVB, 768};
  ca.s[6]  = {d_in[12], WO_CAOW,   32768};
  ca.s[7]  = {d_in[13], WO_CAOB,   256};
  ca.s[8]  = {d_in[14], WO_LN1G,   256};
  ca.s[9]  = {d_in[15], WO_LN1B,   256};
  ca.s[10] = {d_in[16], WO_LN2G,   256};
  ca.s[11] = {d_in[17], WO_LN2B,   256};
  ca.s[12] = {d_in[18], WO_LN3G,   256};
  ca.s[13] = {d_in[19], WO_LN3B,   256};
  ca.s[14] = {d_in[20], WO_FW1,    65536};
  ca.s[15] = {d_in[21], WO_FB1,    512};
  ca.s[16] = {d_in[22], WO_FW2,    65536};
  ca.s[17] = {d_in[23], WO_FB2,    256};
  ca.s[18] = {d_in[24], WO_QW1,    512};
  ca.s[19] = {d_in[25], WO_QB1,    256};
  ca.s[20] = {d_in[26], WO_QW2,    32768};
  ca.s[21] = {d_in[27], WO_QB2,    256};
  ca.s[22] = {d_in[28], WO_KW1,    512};
  ca.s[23] = {d_in[29], WO_KB1,    256};
  ca.s[24] = {d_in[31], WO_KB2,    256};
  ca.s[25] = {d_in[32], WO_PW1,    16384};
  ca.s[26] = {d_in[33], WO_PB1,    128};
  ca.s[27] = {d_in[34], WO_PW2,    768};
  ca.s[28] = {d_in[35], WO_PB2,    6};

  bool big = ws_size >= NEED_BIG + 1024;

  k_cvt<<<dim3(32,8), 256, 0, stream>>>(ca, wb, qlp, p.view, d_in[10], d_in[30],
                                        const_cast<bf16*>(p.wkvT), const_cast<bf16*>(p.kw2T), ln1_g);
  k_stage1<<<4776, 256, 0, stream>>>(p);
  if (big) k_kvproj2<<<1050, 256, 0, stream>>>(p);

  for (int l = 0; l < 2; ++l){
    if (l == 1) k_saq<<<200, 256, 0, stream>>>(p, 1);
    if (!big) k_kvproj1<<<525, 256, 0, stream>>>(p, l);
    k_self<<<200, 256, 0, stream>>>(p, l);
    k_cross_part<<<dim3(NC,8,6), 512, 0, stream>>>(p, big ? l : 0);
    k_tail<<<200, 256, 0, stream>>>(p, l);
  }
}

// Round 15
// 460.844 us; speedup vs baseline: 1.1206x; 1.1206x over previous
//
#include <hip/hip_runtime.h>
#include <hip/hip_bf16.h>
#include <cstdint>
#include <cstddef>

using bf16 = __hip_bfloat16;
#define DEV __device__ __forceinline__

typedef short s16x8 __attribute__((ext_vector_type(8)));
typedef float f32x4 __attribute__((ext_vector_type(4)));

DEV float b2f(bf16 x){ return __bfloat162float(x); }
DEV bf16  f2b(float x){ return __float2bfloat16(x); }
DEV float u2f(unsigned u){ union{unsigned u; float f;} c; c.u=u; return c.f; }
DEV unsigned f2u(float f){ union{float f; unsigned u;} c; c.f=f; return c.u; }
DEV unsigned short f2bu(float f){ unsigned u = f2u(f); u += 0x7FFFu + ((u>>16)&1u); return (unsigned short)(u>>16); }
DEV float sigm(float x){ return 1.f/(1.f+__expf(-x)); }
DEV int get_bf(const void* ln1g){ return ((*(const unsigned*)ln1g) & 0xFFFFu) == 0x3F80u; }

DEV float ld(const void* p, long i, int bf){
  return bf ? b2f(((const bf16*)p)[i]) : ((const float*)p)[i];
}
DEV void st(void* p, long i, float v, int bf){
  if (bf) ((bf16*)p)[i] = f2b(v); else ((float*)p)[i] = v;
}

constexpr float IMGX = 100.0f;
constexpr float IMGY = 56.0f;
constexpr float LOG_EPS = -15.942385f;
constexpr float BIN = 53.0f/1056.0f;
constexpr int NC = 35;
constexpr int CK = 160;

// ---- fp32 weight buffer offsets (floats) ----
constexpr int WO_SAQKVW = 0;
constexpr int WO_SAQKVB = 98304;
constexpr int WO_SAOW   = 99072;
constexpr int WO_SAOB   = 131840;
constexpr int WO_CAQKVW = 132096;
constexpr int WO_CAQKVB = 230400;
constexpr int WO_CAOW   = 231168;
constexpr int WO_CAOB   = 263936;
constexpr int WO_LN1G   = 264192;
constexpr int WO_LN1B   = 264448;
constexpr int WO_LN2G   = 264704;
constexpr int WO_LN2B   = 264960;
constexpr int WO_LN3G   = 265216;
constexpr int WO_LN3B   = 265472;
constexpr int WO_FW1    = 265728;
constexpr int WO_FB1    = 331264;
constexpr int WO_FW2    = 331776;
constexpr int WO_FB2    = 397312;
constexpr int WO_QW1    = 397568;
constexpr int WO_QB1    = 398080;
constexpr int WO_QW2    = 398336;
constexpr int WO_QB2    = 431104;
constexpr int WO_KW1    = 431360;
constexpr int WO_KB1    = 431872;
constexpr int WO_KB2    = 432128;
constexpr int WO_PW1    = 432384;
constexpr int WO_PB1    = 448768;
constexpr int WO_PW2    = 448896;
constexpr int WO_PB2    = 449664;
constexpr int W_TOTAL   = 449680;

// ---- workspace layout (floats) ----
constexpr size_t OFF_Q    = 0;
constexpr size_t OFF_QPE  = 25600;
constexpr size_t OFF_QCA  = 51200;
constexpr size_t OFF_TMP  = 76800;
constexpr size_t OFF_PM   = 153600;
constexpr size_t OFF_PS   = 209600;
constexpr size_t OFF_PO   = 265600;
constexpr size_t OFF_FPOS = 1161600;
constexpr size_t OFF_CTR  = 1172800;
constexpr size_t OFF_SIG  = 1173200;
constexpr size_t OFF_QL   = 1173400;
constexpr size_t OFF_WB   = 1174624;
constexpr size_t F_TOTAL  = OFF_WB + W_TOTAL;
// bf16 region (elements):
constexpr size_t B_KEYS = 0;          // 33600*128
constexpr size_t B_KH   = 4300800;
constexpr size_t B_VH   = 8601600;
constexpr size_t B_KPE  = 12902400;   // 5600*128
constexpr size_t B_WKVT = 13619200;   // 2*256*128
constexpr size_t B_KW2T = 13684736;   // 2*128*128

DEV void unpack2(unsigned u, float* f){ f[0]=u2f(u<<16); f[1]=u2f(u&0xffff0000u); }

DEV float wsum64(float v){
  #pragma unroll
  for (int off=32; off; off>>=1) v += __shfl_xor(v, off);
  return v;
}

// ================= params bundle =================
struct P {
  const void *nifp, *iff, *niqp, *ln1g;
  const int *view, *qlp;
  const float *wb;
  float *q, *qpe, *qca, *tmp, *pm, *ps, *po, *fpos, *ctr, *sig2;
  const bf16 *kw2T, *wkvT, *keys;
  bf16 *kh, *vh, *kpe;
  void *out;
};

// ================= weight conversion + qlist =================
struct Seg { const void* src; int off; int n; };
struct CvtArgs { Seg s[29]; };

__global__ void k_cvt(CvtArgs a, float* dst, int* qlp, const int* view, const void* ln1g){
  if (blockIdx.x == 29){
    int t = threadIdx.x;
    if (blockIdx.y == 0 && t < 6){
      int cnt = 0;
      for (int i = 0; i < 200; ++i)
        if (view[i] == t) qlp[8 + t*200 + cnt++] = i;
      qlp[t] = cnt;
    }
    return;
  }
  int bf = get_bf(ln1g);
  Seg sg = a.s[blockIdx.x];
  for (int i = blockIdx.y*blockDim.x + threadIdx.x; i < sg.n; i += gridDim.y*blockDim.x)
    dst[sg.off + i] = ld(sg.src, i, bf);
}

__global__ __launch_bounds__(128) void k_wT(const void* __restrict__ caw, const void* __restrict__ kw2,
                                            bf16* __restrict__ wkvT, bf16* __restrict__ kw2T,
                                            const void* __restrict__ ln1g){
  int bf = get_bf(ln1g);
  int c = blockIdx.x, l = blockIdx.y, k = threadIdx.x;
  if (c < 256){
    wkvT[((size_t)l*256 + c)*128 + k] = f2b(ld(caw, (long)l*49152 + (long)k*384 + 128 + c, bf));
  } else {
    int cc = c - 256;
    kw2T[((size_t)l*128 + cc)*128 + k] = f2b(ld(kw2, (long)l*16384 + (long)k*128 + cc, bf));
  }
}

// ================= transpose iff -> keys (row-major [v*5600+k][128]) =================
__global__ void k_transpose(const void* __restrict__ iff, bf16* __restrict__ keys,
                            const void* __restrict__ ln1g){
  __shared__ float t[32][33];
  int bf = get_bf(ln1g);
  int k0 = blockIdx.x*32, c0 = blockIdx.y*32, v = blockIdx.z;
  int tx = threadIdx.x, ty = threadIdx.y;
  #pragma unroll
  for (int i=0;i<4;++i){
    int c = c0 + ty + i*8;
    t[ty+i*8][tx] = ld(iff, (long)(v*128 + c)*5600 + k0 + tx, bf);
  }
  __syncthreads();
  #pragma unroll
  for (int i=0;i<4;++i){
    int k = k0 + ty + i*8;
    keys[(size_t)(v*5600 + k)*128 + c0 + tx] = f2b(t[tx][ty+i*8]);
  }
}

// ================= prep2: centers/inverse/pos3d + q-init + pred0 sigma + fpos =================
__global__ __launch_bounds__(128) void k_prep2(
    const void* __restrict__ niqp, const void* __restrict__ l2i, const void* __restrict__ nifp,
    const int* __restrict__ view, const void* __restrict__ iqf,
    float* __restrict__ ctr, float* __restrict__ fpos, float* __restrict__ q,
    const float* __restrict__ wb, float* __restrict__ is2p,
    void* __restrict__ out, const void* __restrict__ ln1g){
  __shared__ float M[16];
  __shared__ float cs[2];
  __shared__ float xs[128];
  __shared__ float acc[6*128];
  __shared__ float bbv[8];
  int bf = get_bf(ln1g);
  int n = blockIdx.x, t = threadIdx.x;
  if (t < 28){
    int k = n*28 + t;
    fpos[2*k]   = sigm(ld(nifp,2*k,bf))*IMGX - 0.5f;
    fpos[2*k+1] = sigm(ld(nifp,2*k+1,bf))*IMGY - 0.5f;
  }
  float xv = ld(iqf, (long)t*200 + n, bf);
  q[(size_t)n*128 + t] = xv;
  xs[t] = xv;
  if (t == 0){
    float p0 = ld(niqp,2*n,bf), p1 = ld(niqp,2*n+1,bf);
    float cx = sigm(p0)*IMGX, cy = sigm(p1)*IMGY;
    ctr[2*n] = cx; ctr[2*n+1] = cy;
    cs[0] = cx; cs[1] = cy;
    st(out, 25600 + 2*n,   p0, bf);
    st(out, 25600 + 2*n+1, p1, bf);
    int v = view[n];
    float a[4][8];
    for (int i=0;i<4;++i)
      for (int jj=0;jj<4;++jj){ a[i][jj] = ld(l2i, v*16+i*4+jj, bf); a[i][4+jj] = (i==jj)?1.f:0.f; }
    for (int col=0; col<4; ++col){
      int p = col; float best = fabsf(a[col][col]);
      for (int r=col+1;r<4;++r){ float tt=fabsf(a[r][col]); if (tt>best){best=tt;p=r;} }
      if (p!=col) for (int jj=0;jj<8;++jj){ float tt=a[col][jj]; a[col][jj]=a[p][jj]; a[p][jj]=tt; }
      float inv = 1.f/a[col][col];
      for (int jj=0;jj<8;++jj) a[col][jj]*=inv;
      for (int r=0;r<4;++r){
        if (r==col) continue;
        float f = a[r][col];
        for (int jj=0;jj<8;++jj) a[r][jj] -= f*a[col][jj];
      }
    }
    for (int i=0;i<4;++i) for (int jj=0;jj<4;++jj) M[i*4+jj] = a[i][4+jj];
  }
  __syncthreads();
  if (t < 32){
    int d = t;
    float px = cs[0]*8.f, py = cs[1]*8.f;
    float dep = 1.f + BIN * (float)d * (float)(d+1);
    float x = px*dep, y = py*dep;
    #pragma unroll
    for (int i=0;i<3;++i){
      float val = M[i*4]*x + M[i*4+1]*y + M[i*4+2]*dep + M[i*4+3];
      st(out, 26000 + n*96 + d*3 + i, val, bf);
    }
  }
  float a = wb[WO_PB1 + t];
  const float* W = wb + WO_PW1;
  for (int k = 0; k < 128; ++k) a = fmaf(xs[k], W[k*128 + t], a);
  float x = fmaxf(a, 0.f);
  #pragma unroll
  for (int c=0;c<6;++c) acc[c*128+t] = x * wb[WO_PW2 + t*6 + c];
  __syncthreads();
  for (int off=64; off; off>>=1){
    if (t < off){
      #pragma unroll
      for (int c=0;c<6;++c) acc[c*128+t] += acc[c*128+t+off];
    }
    __syncthreads();
  }
  if (t < 6) bbv[t] = acc[t*128] + wb[WO_PB2 + t];
  __syncthreads();
  if (t == 0){
    float dxv = sigm(bbv[2]) * IMGX;
    float dyv = sigm(bbv[3]) * IMGY;
    float rad = ceilf(sqrtf(dxv*dxv + dyv*dyv) * 0.5f);
    float sg = (rad*2.f + 1.f) * (1.f/6.f);
    is2p[n] = 1.f/(2.f*sg*sg);
  }
}

// ================= stage bodies =================

// kpe MFMA (writes bf16 kpe), 256 threads, LDS 17.9 KB
DEV void kpe_block(int b, int t, unsigned char* smem, const P& p, int l, int bf){
  constexpr int XP = 136;
  unsigned short* xs = (unsigned short*)smem;
  float2* pr = (float2*)(xs + 64*XP);
  int r0 = b * 64;
  if (t < 64){
    int k = r0 + t; if (k > 5599) k = 5599;
    pr[t] = make_float2(ld(p.nifp,2*k,bf), ld(p.nifp,2*k+1,bf));
  }
  __syncthreads();
  const float* w1 = p.wb + WO_KW1 + l*256;
  const float* b1 = p.wb + WO_KB1 + l*128;
  for (int idx = t; idx < 64*64; idx += 256){
    int r = idx >> 6, c2 = (idx & 63)*2;
    float2 pp = pr[r];
    #pragma unroll
    for (int u=0;u<2;++u){
      int c = c2+u;
      float a = fmaf(pp.x, w1[c], fmaf(pp.y, w1[128+c], b1[c]));
      xs[r*XP + c] = f2bu(fmaxf(a, 0.f));
    }
  }
  int wv = t >> 6;
  int lane = t & 63;
  int l16 = lane & 15, quad = lane >> 4;
  __syncthreads();
  f32x4 acc[4][2];
  #pragma unroll
  for (int mt=0;mt<4;++mt)
    #pragma unroll
    for (int nt=0;nt<2;++nt) acc[mt][nt] = (f32x4){0.f,0.f,0.f,0.f};
  #pragma unroll
  for (int kc = 0; kc < 4; ++kc){
    s16x8 bfr[2];
    #pragma unroll
    for (int nt = 0; nt < 2; ++nt){
      int col = wv*32 + nt*16 + l16;
      bfr[nt] = *(const s16x8*)&p.kw2T[((size_t)l*128 + col)*128 + kc*32 + quad*8];
    }
    s16x8 afr[4];
    #pragma unroll
    for (int mt = 0; mt < 4; ++mt)
      afr[mt] = *(const s16x8*)&xs[(mt*16 + l16)*XP + kc*32 + quad*8];
    #pragma unroll
    for (int mt = 0; mt < 4; ++mt)
      #pragma unroll
      for (int nt = 0; nt < 2; ++nt)
        acc[mt][nt] = __builtin_amdgcn_mfma_f32_16x16x32_bf16(afr[mt], bfr[nt], acc[mt][nt], 0, 0, 0);
  }
  float bv[2];
  #pragma unroll
  for (int nt=0;nt<2;++nt) bv[nt] = p.wb[WO_KB2 + l*128 + wv*32 + nt*16 + l16];
  #pragma unroll
  for (int mt = 0; mt < 4; ++mt)
    #pragma unroll
    for (int i = 0; i < 4; ++i){
      int gr = r0 + mt*16 + quad*4 + i;
      if (gr < 5600){
        #pragma unroll
        for (int nt = 0; nt < 2; ++nt)
          p.kpe[(size_t)gr*128 + wv*32 + nt*16 + l16] = f2b(acc[mt][nt][i] + bv[nt]);
      }
    }
}

// saqkv: qpe MLP + sa_qkv projection, 256 threads, LDS 1 KB
DEV void saqkv_block(int n, int t, unsigned char* smem, const P& p, int l, int bf){
  float* hs = (float*)smem;      // 128
  float* xq = hs + 128;          // 128
  if (t < 128){
    float p0 = ld(p.niqp,2*n,bf), p1 = ld(p.niqp,2*n+1,bf);
    float a = fmaf(p0, p.wb[WO_QW1 + l*256 + t], fmaf(p1, p.wb[WO_QW1 + l*256 + 128 + t], p.wb[WO_QB1 + l*128 + t]));
    hs[t] = fmaxf(a, 0.f);
  }
  __syncthreads();
  if (t < 128){
    const float* W = p.wb + WO_QW2 + l*16384;
    float a = p.wb[WO_QB2 + l*128 + t];
    for (int k = 0; k < 128; ++k) a = fmaf(hs[k], W[k*128 + t], a);
    p.qpe[(size_t)n*128 + t] = a;
    xq[t] = p.q[(size_t)n*128 + t] + a;
  }
  __syncthreads();
  const float* W = p.wb + WO_SAQKVW + l*49152;
  for (int c = t; c < 384; c += 256){
    float acc = p.wb[WO_SAQKVB + l*384 + c];
    for (int k = 0; k < 128; ++k) acc = fmaf(xq[k], W[(long)k*384 + c], acc);
    p.tmp[(size_t)n*384 + c] = acc;
  }
}

// kv projection MFMA (keys + kpe -> kh/vh), 256 threads, LDS 17.4 KB
DEV void kvproj_block(int b, int t, unsigned char* smem, const P& p, int l){
  constexpr int XP = 136;
  unsigned short* xs = (unsigned short*)smem;
  int r0 = b * 64;
  for (int idx = t; idx < 64*64; idx += 256){
    int r = idx >> 6, c2 = (idx & 63)*2;
    int gr = r0 + r;
    int v = gr / 5600; int k = gr - v*5600;
    float a0 = b2f(p.keys[(size_t)gr*128 + c2])   + b2f(p.kpe[(size_t)k*128 + c2]);
    float a1 = b2f(p.keys[(size_t)gr*128 + c2+1]) + b2f(p.kpe[(size_t)k*128 + c2+1]);
    xs[r*XP + c2]   = f2bu(a0);
    xs[r*XP + c2+1] = f2bu(a1);
  }
  int wv = t >> 6;
  int lane = t & 63;
  int l16 = lane & 15, quad = lane >> 4;
  __syncthreads();
  f32x4 acc[4][4];
  #pragma unroll
  for (int mt=0;mt<4;++mt)
    #pragma unroll
    for (int nt=0;nt<4;++nt) acc[mt][nt] = (f32x4){0.f,0.f,0.f,0.f};
  #pragma unroll
  for (int kc = 0; kc < 4; ++kc){
    s16x8 bfr[4];
    #pragma unroll
    for (int nt = 0; nt < 4; ++nt){
      int col = wv*64 + nt*16 + l16;
      bfr[nt] = *(const s16x8*)&p.wkvT[((size_t)l*256 + col)*128 + kc*32 + quad*8];
    }
    s16x8 afr[4];
    #pragma unroll
    for (int mt = 0; mt < 4; ++mt)
      afr[mt] = *(const s16x8*)&xs[(mt*16 + l16)*XP + kc*32 + quad*8];
    #pragma unroll
    for (int mt = 0; mt < 4; ++mt)
      #pragma unroll
      for (int nt = 0; nt < 4; ++nt)
        acc[mt][nt] = __builtin_amdgcn_mfma_f32_16x16x32_bf16(afr[mt], bfr[nt], acc[mt][nt], 0, 0, 0);
  }
  float bv[4];
  bf16* op[4];
  long ntOff[4];
  #pragma unroll
  for (int nt = 0; nt < 4; ++nt){
    int c = wv*64 + nt*16 + l16;
    bv[nt] = p.wb[WO_CAQKVB + l*384 + 128 + c];
    int sel = c >> 7, ch = c & 127;
    int h = ch >> 4, d = ch & 15;
    op[nt] = sel ? p.vh : p.kh;
    ntOff[nt] = (long)h*89600 + d;
  }
  #pragma unroll
  for (int mt = 0; mt < 4; ++mt)
    #pragma unroll
    for (int i = 0; i < 4; ++i){
      int gr = r0 + mt*16 + quad*4 + i;
      int v = gr / 5600; int k = gr - v*5600;
      long rowOff = (long)v*716800 + (long)k*16;
      #pragma unroll
      for (int nt = 0; nt < 4; ++nt)
        op[nt][rowOff + ntOff[nt]] = f2b(acc[mt][nt][i] + bv[nt]);
    }
}

// self-attn + out-proj + LN1 + ca-q projection, 256 threads, LDS 2 KB
DEV void selfattn_block(int n, int t, unsigned char* smem, const P& p, int l){
  float* att  = (float*)smem;    // 128
  float* part = att + 128;       // 256
  float* redw = part + 256;      // 4
  float* xs2  = redw + 4;        // 128
  int h = t >> 5, j = t & 31;
  int vn = p.view[n];
  float qh[16];
  #pragma unroll
  for (int d=0; d<16; ++d) qh[d] = p.tmp[(size_t)n*384 + h*16 + d] * 0.25f;
  float m = -INFINITY, s = 0.f, o[16];
  #pragma unroll
  for (int d=0; d<16; ++d) o[d]=0.f;
  for (int k = j; k < 200; k += 32){
    float l2;
    if (p.view[k] != vn){ l2 = -INFINITY; }
    else {
      const float* kr = p.tmp + (size_t)k*384 + 128 + h*16;
      l2 = 0.f;
      #pragma unroll
      for (int d=0; d<16; ++d) l2 = fmaf(qh[d], kr[d], l2);
    }
    float mn = fmaxf(m, l2);
    float ea = (m > -3.0e38f) ? __expf(m - mn) : 0.f;
    float pp = (l2 > -3.0e38f) ? __expf(l2 - mn) : 0.f;
    s = s*ea + pp;
    const float* vr = p.tmp + (size_t)k*384 + 256 + h*16;
    #pragma unroll
    for (int d=0; d<16; ++d) o[d] = o[d]*ea + pp*vr[d];
    m = mn;
  }
  // max-first merge across 32 lanes
  float M = m;
  #pragma unroll
  for (int off=16; off>=1; off>>=1) M = fmaxf(M, __shfl_xor(M, off));
  float sc = (m > -3.0e38f) ? __expf(m - M) : 0.f;
  s *= sc;
  #pragma unroll
  for (int d=0; d<16; ++d) o[d] *= sc;
  #pragma unroll
  for (int off=16; off>=1; off>>=1){
    s += __shfl_xor(s, off);
    #pragma unroll
    for (int d=0; d<16; ++d) o[d] += __shfl_xor(o[d], off);
  }
  if (j == 0){
    float inv = (s > 0.f) ? 1.f/s : 0.f;
    #pragma unroll
    for (int d=0; d<16; ++d) att[h*16 + d] = o[d]*inv;
  }
  __syncthreads();
  int tc = t & 127, half = t >> 7;
  {
    const float* W = p.wb + WO_SAOW + l*16384;
    float a = 0.f;
    for (int k = half*64; k < half*64+64; ++k) a = fmaf(att[k], W[k*128 + tc], a);
    part[t] = a;
  }
  __syncthreads();
  float v = (t<128) ? p.q[(size_t)n*128 + t] + part[t] + part[128+t] + p.wb[WO_SAOB + l*128 + t] : 0.f;
  float sv = wsum64(v);
  if ((t&63)==0) redw[t>>6] = sv;
  __syncthreads();
  float mean = (redw[0]+redw[1]+redw[2]+redw[3]) * (1.f/128.f);
  __syncthreads();
  float d = (t<128)? v-mean : 0.f;
  sv = wsum64(d*d);
  if ((t&63)==0) redw[t>>6] = sv;
  __syncthreads();
  float var = (redw[0]+redw[1]+redw[2]+redw[3]) * (1.f/128.f);
  float r = rsqrtf(var + 1e-5f);
  if (t<128){
    float qn = d*r*p.wb[WO_LN1G + l*128 + t] + p.wb[WO_LN1B + l*128 + t];
    p.q[(size_t)n*128 + t] = qn;
    xs2[t] = qn + p.qpe[(size_t)n*128 + t];
  }
  __syncthreads();
  {
    const float* Wc = p.wb + WO_CAQKVW + l*49152;
    float a = 0.f;
    for (int k = half*64; k < half*64+64; ++k) a = fmaf(xs2[k], Wc[(long)k*384 + tc], a);
    part[t] = a;
  }
  __syncthreads();
  if (t<128)
    p.qca[(size_t)n*128 + t] = part[t] + part[128+t] + p.wb[WO_CAQKVB + l*384 + t];
}

// ================= packed launches =================
__global__ __launch_bounds__(256) void k_packA(P p, int l){
  __shared__ __align__(16) unsigned char smem[17920];
  int bf = get_bf(p.ln1g);
  int b = blockIdx.x;
  if (b < 88) kpe_block(b, threadIdx.x, smem, p, l, bf);
  else        saqkv_block(b - 88, threadIdx.x, smem, p, l, bf);
}

__global__ __launch_bounds__(256) void k_packB(P p, int l){
  __shared__ __align__(16) unsigned char smem[17408];
  int b = blockIdx.x;
  if (b < 525) kvproj_block(b, threadIdx.x, smem, p, l);
  else         selfattn_block(b - 525, threadIdx.x, smem, p, l);
}

// ================= cross-attention partial =================
__global__ __launch_bounds__(256) void k_cross_part(P p){
  __shared__ __align__(16) unsigned short KV[CK][36];
  __shared__ float2 fp[CK];
  int ch = blockIdx.x, h = blockIdx.y, v = blockIdx.z;
  int t = threadIdx.x;
  int k0 = ch*CK;
  const uint2* ks = (const uint2*)(p.kh + ((size_t)(v*8 + h)*5600 + k0)*16);
  const uint2* vs = (const uint2*)(p.vh + ((size_t)(v*8 + h)*5600 + k0)*16);
  for (int i = t; i < CK*4; i += 256){
    int key = i >> 2, part = i & 3;
    *(uint2*)&KV[key][part*4]      = ks[i];
    *(uint2*)&KV[key][16 + part*4] = vs[i];
  }
  if (t < CK) fp[t] = ((const float2*)p.fpos)[k0 + t];
  __syncthreads();
  int nq = p.qlp[v];
  const int* ql = p.qlp + 8 + v*200;
  int g = t >> 5, j = t & 31;
  for (int pp = g; pp < nq; pp += 8){
    int n = ql[pp];
    float cx = p.ctr[2*n], cy = p.ctr[2*n+1];
    float is2 = p.sig2[n];
    float qh[16];
    const float* qrow = p.qca + (size_t)n*128 + h*16;
    #pragma unroll
    for (int d=0; d<16; ++d) qh[d] = qrow[d] * 0.25f;
    float m = -INFINITY, s = 0.f, o[16];
    #pragma unroll
    for (int d=0; d<16; ++d) o[d]=0.f;
    #pragma unroll
    for (int i = 0; i < CK/32; ++i){
      int key = i*32 + j;
      float2 pxy = fp[key];
      float dx = cx - pxy.x, dy = cy - pxy.y;
      float gg = -(dx*dx + dy*dy) * is2;
      const uint2* kp = (const uint2*)&KV[key][0];
      const uint2* vp = (const uint2*)&KV[key][16];
      float kf[16], vf[16];
      #pragma unroll
      for (int u=0; u<4; ++u){
        uint2 a = kp[u]; unpack2(a.x, kf+u*4); unpack2(a.y, kf+u*4+2);
        uint2 b = vp[u]; unpack2(b.x, vf+u*4); unpack2(b.y, vf+u*4+2);
      }
      float l = gg;
      #pragma unroll
      for (int d=0; d<16; ++d) l = fmaf(qh[d], kf[d], l);
      l = (gg < LOG_EPS) ? -INFINITY : l;
      float mn = fmaxf(m, l);
      float ea = (m > -3.0e38f) ? __expf(m - mn) : 0.f;
      float pr = (l > -3.0e38f) ? __expf(l - mn) : 0.f;
      s = s*ea + pr;
      #pragma unroll
      for (int d=0; d<16; ++d) o[d] = o[d]*ea + pr*vf[d];
      m = mn;
    }
    float M = m;
    #pragma unroll
    for (int off=16; off>=1; off>>=1) M = fmaxf(M, __shfl_xor(M, off));
    float sc = (m > -3.0e38f) ? __expf(m - M) : 0.f;
    s *= sc;
    #pragma unroll
    for (int d=0; d<16; ++d) o[d] *= sc;
    #pragma unroll
    for (int off=16; off>=1; off>>=1){
      s += __shfl_xor(s, off);
      #pragma unroll
      for (int d=0; d<16; ++d) o[d] += __shfl_xor(o[d], off);
    }
    if (j == 0){
      int idx = (n*NC + ch)*8 + h;
      p.pm[idx] = M; p.ps[idx] = s;
      float4* o4 = (float4*)(p.po + (size_t)idx*16);
      o4[0] = make_float4(o[0],o[1],o[2],o[3]);
      o4[1] = make_float4(o[4],o[5],o[6],o[7]);
      o4[2] = make_float4(o[8],o[9],o[10],o[11]);
      o4[3] = make_float4(o[12],o[13],o[14],o[15]);
    }
  }
}

// ================= tail =================
__global__ __launch_bounds__(256) void k_tail(P p, int l){
  __shared__ float att[128];
  __shared__ float sm[2][128], ss[2][128], so[2][128];
  __shared__ float part[256];
  __shared__ float redw[4];
  __shared__ float xs[128];
  __shared__ float hs[256];
  __shared__ float ac6[6*128];
  __shared__ float bbv[8];
  int bf = get_bf(p.ln1g);
  int n = blockIdx.x, t = threadIdx.x;
  long outOff = (l==0) ? 45200L : 46400L;
  int last = (l==1);
  int tc = t & 127, half = t >> 7;
  {
    int h = tc >> 4, d = tc & 15;
    int c0 = half ? 18 : 0, c1 = half ? NC : 18;
    float m = -INFINITY, s = 0.f, o = 0.f;
    for (int c = c0; c < c1; ++c){
      int idx = (n*NC + c)*8 + h;
      float mc = p.pm[idx], sc = p.ps[idx], oc = p.po[(size_t)idx*16 + d];
      float mn = fmaxf(m, mc);
      float ea = (m  > -3.0e38f) ? __expf(m  - mn) : 0.f;
      float eb = (mc > -3.0e38f) ? __expf(mc - mn) : 0.f;
      s = s*ea + sc*eb;
      o = o*ea + oc*eb;
      m = mn;
    }
    sm[half][tc]=m; ss[half][tc]=s; so[half][tc]=o;
  }
  __syncthreads();
  if (t < 128){
    float m1=sm[0][t], m2=sm[1][t];
    float mn=fmaxf(m1,m2);
    float e1=(m1>-3.0e38f)?__expf(m1-mn):0.f, e2=(m2>-3.0e38f)?__expf(m2-mn):0.f;
    float s = ss[0][t]*e1 + ss[1][t]*e2;
    float o = so[0][t]*e1 + so[1][t]*e2;
    att[t] = (s>0.f)? o/s : 0.f;
  }
  __syncthreads();
  {
    const float* W = p.wb + WO_CAOW + l*16384;
    float a = 0.f;
    for (int k = half*64; k < half*64+64; ++k) a = fmaf(att[k], W[k*128 + tc], a);
    part[t] = a;
  }
  __syncthreads();
  float v = (t<128) ? p.q[(size_t)n*128 + t] + part[t] + part[128+t] + p.wb[WO_CAOB + l*128 + t] : 0.f;
  float sv = wsum64(v);
  if ((t&63)==0) redw[t>>6] = sv;
  __syncthreads();
  float mean = (redw[0]+redw[1]+redw[2]+redw[3]) * (1.f/128.f);
  __syncthreads();
  float d = (t<128)? v-mean : 0.f;
  sv = wsum64(d*d);
  if ((t&63)==0) redw[t>>6] = sv;
  __syncthreads();
  float var = (redw[0]+redw[1]+redw[2]+redw[3]) * (1.f/128.f);
  float r = rsqrtf(var + 1e-5f);
  if (t<128) xs[t] = d*r*p.wb[WO_LN2G + l*128 + t] + p.wb[WO_LN2B + l*128 + t];
  __syncthreads();
  {
    const float* W = p.wb + WO_FW1 + l*32768;
    float a = p.wb[WO_FB1 + l*256 + t];
    for (int k=0;k<128;++k) a = fmaf(xs[k], W[k*256 + t], a);
    hs[t] = fmaxf(a, 0.f);
  }
  __syncthreads();
  {
    const float* W = p.wb + WO_FW2 + l*32768;
    float a = 0.f;
    for (int k=half*128;k<half*128+128;++k) a = fmaf(hs[k], W[k*128 + tc], a);
    part[t] = a;
  }
  __syncthreads();
  v = (t<128) ? xs[t] + part[t] + part[128+t] + p.wb[WO_FB2 + l*128 + t] : 0.f;
  sv = wsum64(v);
  if ((t&63)==0) redw[t>>6] = sv;
  __syncthreads();
  mean = (redw[0]+redw[1]+redw[2]+redw[3]) * (1.f/128.f);
  __syncthreads();
  d = (t<128)? v-mean : 0.f;
  sv = wsum64(d*d);
  if ((t&63)==0) redw[t>>6] = sv;
  __syncthreads();
  var = (redw[0]+redw[1]+redw[2]+redw[3]) * (1.f/128.f);
  r = rsqrtf(var + 1e-5f);
  if (t<128){
    float q3 = d*r*p.wb[WO_LN3G + l*128 + t] + p.wb[WO_LN3B + l*128 + t];
    p.q[(size_t)n*128 + t] = q3;
    xs[t] = q3;
    if (last) st(p.out, (long)t*200 + n, q3, bf);
  }
  __syncthreads();
  {
    const float* W = p.wb + WO_PW1;
    float a = 0.f;
    for (int k=half*64;k<half*64+64;++k) a = fmaf(xs[k], W[k*128 + tc], a);
    part[t] = a;
  }
  __syncthreads();
  if (t<128){
    float x = fmaxf(part[t] + part[128+t] + p.wb[WO_PB1 + t], 0.f);
    #pragma unroll
    for (int c=0;c<6;++c) ac6[c*128+t] = x * p.wb[WO_PW2 + t*6 + c];
  }
  __syncthreads();
  for (int off=64; off; off>>=1){
    if (t < off){
      #pragma unroll
      for (int c=0;c<6;++c) ac6[c*128+t] += ac6[c*128+t+off];
    }
    __syncthreads();
  }
  if (t < 6){
    float raw = ac6[t*128] + p.wb[WO_PB2 + t];
    if (t < 2) raw += ld(p.niqp, 2*n + t, bf);
    float svv = sigm(raw);
    st(p.out, outOff + n*6 + t, svv, bf);
    bbv[t] = svv;
  }
  __syncthreads();
  if (t == 0){
    float dxv = sigm(bbv[2]) * IMGX;
    float dyv = sigm(bbv[3]) * IMGY;
    float rad = ceilf(sqrtf(dxv*dxv + dyv*dyv) * 0.5f);
    float sg = (rad*2.f + 1.f) * (1.f/6.f);
    p.sig2[n] = 1.f/(2.f*sg*sg);
  }
}

// ================= launch =================
extern "C" void kernel_launch(void* const* d_in, const int* in_sizes, int n_in,
                              void* d_out, int out_size, void* d_ws, size_t ws_size,
                              hipStream_t stream){
  const void* iqf   = d_in[0];
  const void* niqp  = d_in[1];
  const void* iff   = d_in[2];
  const void* nifp  = d_in[3];
  const void* l2i   = d_in[4];
  const int*  view  = (const int*)d_in[5];
  const void* ln1_g = d_in[14];

  float* fw = (float*)d_ws;
  int*   qlp  = (int*)(fw + OFF_QL);
  float* wb   = fw + OFF_WB;
  bf16* bw   = (bf16*)((char*)d_ws + F_TOTAL*sizeof(float));
  bf16* wkvT_m = bw + B_WKVT;
  bf16* kw2T_m = bw + B_KW2T;

  P p;
  p.nifp = nifp; p.iff = iff; p.niqp = niqp; p.ln1g = ln1_g;
  p.view = view; p.qlp = qlp;
  p.wb = wb;
  p.q = fw + OFF_Q; p.qpe = fw + OFF_QPE; p.qca = fw + OFF_QCA; p.tmp = fw + OFF_TMP;
  p.pm = fw + OFF_PM; p.ps = fw + OFF_PS; p.po = fw + OFF_PO;
  p.fpos = fw + OFF_FPOS; p.ctr = fw + OFF_CTR; p.sig2 = fw + OFF_SIG;
  p.kw2T = kw2T_m; p.wkvT = wkvT_m; p.keys = bw + B_KEYS;
  p.kh = bw + B_KH; p.vh = bw + B_VH; p.kpe = bw + B_KPE;
  p.out = d_out;

  CvtArgs ca;
  ca.s[0]  = {d_in[6],  WO_SAQKVW, 98304};
  ca.s[1]  = {d_in[7],  WO_SAQKVB, 768};
  ca.s[2]  = {d_in[8],  WO_SAOW,   32768};
  ca.s[3]  = {d_in[9],  WO_SAOB,   256};
  ca.s[4]  = {d_in[10], WO_CAQKVW, 98304};
  ca.s[5]  = {d_in[11], WO_CAQKVB, 768};
  ca.s[6]  = {d_in[12], WO_CAOW,   32768};
  ca.s[7]  = {d_in[13], WO_CAOB,   256};
  ca.s[8]  = {d_in[14], WO_LN1G,   256};
  ca.s[9]  = {d_in[15], WO_LN1B,   256};
  ca.s[10] = {d_in[16], WO_LN2G,   256};
  ca.s[11] = {d_in[17], WO_LN2B,   256};
  ca.s[12] = {d_in[18], WO_LN3G,   256};
  ca.s[13] = {d_in[19], WO_LN3B,   256};
  ca.s[14] = {d_in[20], WO_FW1,    65536};
  ca.s[15] = {d_in[21], WO_FB1,    512};
  ca.s[16] = {d_in[22], WO_FW2,    65536};
  ca.s[17] = {d_in[23], WO_FB2,    256};
  ca.s[18] = {d_in[24], WO_QW1,    512};
  ca.s[19] = {d_in[25], WO_QB1,    256};
  ca.s[20] = {d_in[26], WO_QW2,    32768};
  ca.s[21] = {d_in[27], WO_QB2,    256};
  ca.s[22] = {d_in[28], WO_KW1,    512};
  ca.s[23] = {d_in[29], WO_KB1,    256};
  ca.s[24] = {d_in[31], WO_KB2,    256};
  ca.s[25] = {d_in[32], WO_PW1,    16384};
  ca.s[26] = {d_in[33], WO_PB1,    128};
  ca.s[27] = {d_in[34], WO_PW2,    768};
  ca.s[28] = {d_in[35], WO_PB2,    6};

  k_cvt<<<dim3(30,8), 256, 0, stream>>>(ca, wb, qlp, view, ln1_g);
  k_wT<<<dim3(384,2), 128, 0, stream>>>(d_in[10], d_in[30], wkvT_m, kw2T_m, ln1_g);
  k_transpose<<<dim3(175,4,6), dim3(32,8), 0, stream>>>(iff, bw + B_KEYS, ln1_g);
  k_prep2<<<200, 128, 0, stream>>>(niqp, l2i, nifp, view, iqf, p.ctr, p.fpos, p.q, wb, p.sig2, d_out, ln1_g);

  for (int l = 0; l < 2; ++l){
    k_packA<<<288, 256, 0, stream>>>(p, l);
    k_packB<<<725, 256, 0, stream>>>(p, l);
    k_cross_part<<<dim3(NC,8,6), 256, 0, stream>>>(p);
    k_tail<<<200, 256, 0, stream>>>(p, l);
  }
}